// Round 4
// baseline (646.122 us; speedup 1.0000x reference)
//
#include <hip/hip_runtime.h>
#include <hip/hip_bf16.h>

#define H 256
#define NTHREADS 256

// ---------- helpers ----------
static __device__ __forceinline__ float bf2f(unsigned short u) {
    return __uint_as_float(((unsigned int)u) << 16);
}
static __device__ __forceinline__ unsigned short f2bf(float f) {
    unsigned int x = __float_as_uint(f);
    // round-to-nearest-even
    unsigned int r = (x + 0x7fffu + ((x >> 16) & 1u)) >> 16;
    return (unsigned short)r;
}

// ---------- cast x (f32 -> bf16) ----------
__global__ __launch_bounds__(NTHREADS) void cast_x_kernel(
    const float* __restrict__ x, unsigned short* __restrict__ h, int n4)
{
    int i = blockIdx.x * NTHREADS + threadIdx.x;
    if (i < n4) {
        float4 v = ((const float4*)x)[i];
        ushort4 o;
        o.x = f2bf(v.x); o.y = f2bf(v.y); o.z = f2bf(v.z); o.w = f2bf(v.w);
        ((ushort4*)h)[i] = o;
    }
}

// ---------- build Bcat[j][k]: k<256 -> Wl[j][k], else Wr[j][k-256] (bf16) ----------
__global__ __launch_bounds__(NTHREADS) void cast_w_kernel(
    const float* __restrict__ Wl, const float* __restrict__ Wr,
    unsigned short* __restrict__ Bcat)
{
    int i = blockIdx.x * NTHREADS + threadIdx.x;   // 256*512 elements
    int j = i >> 9;
    int k = i & 511;
    float v = (k < H) ? Wl[j * H + k] : Wr[j * H + (k - H)];
    Bcat[i] = f2bf(v);
}

// ---------- degree histogram ----------
__global__ __launch_bounds__(NTHREADS) void hist_kernel(
    const int* __restrict__ dst, int* __restrict__ cnt, int E)
{
    int i = blockIdx.x * NTHREADS + threadIdx.x;
    if (i < E) atomicAdd(&cnt[dst[i]], 1);
}

// ---------- multi-block exclusive scan, stage 1: per-block scan ----------
__global__ __launch_bounds__(NTHREADS) void scan_partial_kernel(
    const int* __restrict__ cnt, int* __restrict__ row_ptr,
    int* __restrict__ blocksum, int n_nodes)
{
    __shared__ int tmp[NTHREADS];
    int t = threadIdx.x;
    int i = blockIdx.x * NTHREADS + t;
    int v = (i < n_nodes) ? cnt[i] : 0;
    tmp[t] = v;
    __syncthreads();
#pragma unroll
    for (int d = 1; d < NTHREADS; d <<= 1) {
        int add = (t >= d) ? tmp[t - d] : 0;
        __syncthreads();
        tmp[t] += add;
        __syncthreads();
    }
    if (i < n_nodes) row_ptr[i] = tmp[t] - v;   // exclusive
    if (t == NTHREADS - 1) blocksum[blockIdx.x] = tmp[t];
}

// ---------- stage 2: single block scans block sums (nb <= 256) ----------
__global__ __launch_bounds__(NTHREADS) void scan_sums_kernel(
    int* __restrict__ blocksum, int* __restrict__ blockoff,
    int* __restrict__ row_ptr, int n_blocks, int n_nodes)
{
    __shared__ int tmp[NTHREADS];
    int t = threadIdx.x;
    int v = (t < n_blocks) ? blocksum[t] : 0;
    tmp[t] = v;
    __syncthreads();
#pragma unroll
    for (int d = 1; d < NTHREADS; d <<= 1) {
        int add = (t >= d) ? tmp[t - d] : 0;
        __syncthreads();
        tmp[t] += add;
        __syncthreads();
    }
    if (t < n_blocks) blockoff[t] = tmp[t] - v;  // exclusive
    if (t == NTHREADS - 1) row_ptr[n_nodes] = tmp[t];  // grand total (== E)
}

// ---------- stage 3: add block offsets, init cursor/deg_inv ----------
__global__ __launch_bounds__(NTHREADS) void scan_finish_kernel(
    const int* __restrict__ cnt, int* __restrict__ row_ptr,
    int* __restrict__ cursor, float* __restrict__ deg_inv,
    const int* __restrict__ blockoff, int n_nodes)
{
    int i = blockIdx.x * NTHREADS + threadIdx.x;
    if (i < n_nodes) {
        int r = row_ptr[i] + blockoff[blockIdx.x];
        row_ptr[i] = r;
        cursor[i] = r;
        deg_inv[i] = 1.0f / (float)max(cnt[i], 1);
    }
}

// ---------- scatter edges into CSR order ----------
__global__ __launch_bounds__(NTHREADS) void fill_kernel(
    const int* __restrict__ src, const int* __restrict__ dst,
    int* __restrict__ cursor, int* __restrict__ csr_src, int E)
{
    int i = blockIdx.x * NTHREADS + threadIdx.x;
    if (i < E) {
        int p = atomicAdd(&cursor[dst[i]], 1);
        csr_src[p] = src[i];
    }
}

// ---------- mean aggregation: one wave per node ----------
__global__ __launch_bounds__(NTHREADS) void agg_kernel(
    const unsigned short* __restrict__ h, const int* __restrict__ row_ptr,
    const int* __restrict__ csr_src, const float* __restrict__ deg_inv,
    unsigned short* __restrict__ agg, int n_nodes)
{
    int wave = threadIdx.x >> 6;
    int lane = threadIdx.x & 63;
    int node = blockIdx.x * 4 + wave;
    if (node >= n_nodes) return;
    int beg = row_ptr[node];
    int end = row_ptr[node + 1];
    float a0 = 0.f, a1 = 0.f, a2 = 0.f, a3 = 0.f;
    for (int e = beg; e < end; e += 64) {
        int cnt = min(64, end - e);
        int idx = (lane < cnt) ? csr_src[e + lane] : 0;
        int j = 0;
        for (; j + 1 < cnt; j += 2) {
            int s0 = __shfl(idx, j);
            int s1 = __shfl(idx, j + 1);
            ushort4 v0 = *(const ushort4*)(h + (size_t)s0 * H + lane * 4);
            ushort4 v1 = *(const ushort4*)(h + (size_t)s1 * H + lane * 4);
            a0 += bf2f(v0.x); a1 += bf2f(v0.y); a2 += bf2f(v0.z); a3 += bf2f(v0.w);
            a0 += bf2f(v1.x); a1 += bf2f(v1.y); a2 += bf2f(v1.z); a3 += bf2f(v1.w);
        }
        if (j < cnt) {
            int s0 = __shfl(idx, j);
            ushort4 v0 = *(const ushort4*)(h + (size_t)s0 * H + lane * 4);
            a0 += bf2f(v0.x); a1 += bf2f(v0.y); a2 += bf2f(v0.z); a3 += bf2f(v0.w);
        }
    }
    float di = deg_inv[node];
    ushort4 o;
    o.x = f2bf(a0 * di); o.y = f2bf(a1 * di); o.z = f2bf(a2 * di); o.w = f2bf(a3 * di);
    *(ushort4*)(agg + (size_t)node * H + lane * 4) = o;
}

// ---------- LDS-free fused GEMM: out = [agg|hin](M x 512) @ Bcat^T(512 x 256) + bias, ELU ----
// Each wave owns an independent 64x64 output tile; MFMA A/B fragments are loaded
// DIRECTLY from global (16B contiguous per lane, L1/L2-resident operands).
// No __shared__, no __syncthreads, no vmcnt(0) barrier drains. 4 waves of a block
// share the same A rows (L1 reuse) and cover the 4 n-tiles of N=256.
typedef __bf16 bf16x8 __attribute__((ext_vector_type(8)));
typedef float f32x4 __attribute__((ext_vector_type(4)));

__global__ __launch_bounds__(NTHREADS) void gemm_kernel(
    const unsigned short* __restrict__ Agg, const unsigned short* __restrict__ Hin,
    const unsigned short* __restrict__ Bcat, const float* __restrict__ bias,
    unsigned short* __restrict__ outb, float* __restrict__ outf, int M)
{
    const int lane = threadIdx.x & 63;
    const int wave = threadIdx.x >> 6;
    const int m0 = blockIdx.x * 64;
    const int n0 = wave * 64;                 // 4 waves cover N=256
    const int lrow = lane & 15;
    const int kc8 = (lane >> 4) * 8;          // k-offset of this lane's 8-elem chunk

    f32x4 acc[4][4] = {};                     // [i2 (m-sub)][jj (n-sub)]

    // clamped A-row ids (tail tile duplicates last row; stores are guarded)
    int arow[4];
#pragma unroll
    for (int i2 = 0; i2 < 4; ++i2) arow[i2] = min(m0 + i2 * 16 + lrow, M - 1);

    const unsigned short* bb = Bcat + (size_t)(n0 + lrow) * 512 + kc8;

    // ---- first half of K: A = Agg, k in [0,256) ----
#pragma unroll 2
    for (int ks = 0; ks < 256; ks += 32) {
        bf16x8 a[4], b[4];
#pragma unroll
        for (int i2 = 0; i2 < 4; ++i2)
            a[i2] = *(const bf16x8*)(Agg + (size_t)arow[i2] * H + ks + kc8);
#pragma unroll
        for (int jj = 0; jj < 4; ++jj)
            b[jj] = *(const bf16x8*)(bb + (size_t)jj * 16 * 512 + ks);
#pragma unroll
        for (int i2 = 0; i2 < 4; ++i2)
#pragma unroll
            for (int jj = 0; jj < 4; ++jj)
                acc[i2][jj] = __builtin_amdgcn_mfma_f32_16x16x32_bf16(
                    a[i2], b[jj], acc[i2][jj], 0, 0, 0);
    }
    // ---- second half of K: A = Hin, k in [256,512) ----
#pragma unroll 2
    for (int ks = 0; ks < 256; ks += 32) {
        bf16x8 a[4], b[4];
#pragma unroll
        for (int i2 = 0; i2 < 4; ++i2)
            a[i2] = *(const bf16x8*)(Hin + (size_t)arow[i2] * H + ks + kc8);
#pragma unroll
        for (int jj = 0; jj < 4; ++jj)
            b[jj] = *(const bf16x8*)(bb + (size_t)jj * 16 * 512 + 256 + ks);
#pragma unroll
        for (int i2 = 0; i2 < 4; ++i2)
#pragma unroll
            for (int jj = 0; jj < 4; ++jj)
                acc[i2][jj] = __builtin_amdgcn_mfma_f32_16x16x32_bf16(
                    a[i2], b[jj], acc[i2][jj], 0, 0, 0);
    }

    // epilogue: bias + ELU; D layout: col = lane&15, row = (lane>>4)*4 + reg
    const int rgrp = (lane >> 4) * 4;
#pragma unroll
    for (int jj = 0; jj < 4; ++jj) {
        int n = n0 + jj * 16 + lrow;
        float bn = bias[n];
#pragma unroll
        for (int i2 = 0; i2 < 4; ++i2) {
#pragma unroll
            for (int reg = 0; reg < 4; ++reg) {
                int m = m0 + i2 * 16 + rgrp + reg;
                if (m < M) {
                    float v = acc[i2][jj][reg] + bn;
                    v = (v > 0.f) ? v : expm1f(v);
                    if (outf) outf[(size_t)m * H + n] = v;
                    else      outb[(size_t)m * H + n] = f2bf(v);
                }
            }
        }
    }
}

extern "C" void kernel_launch(void* const* d_in, const int* in_sizes, int n_in,
                              void* d_out, int out_size, void* d_ws, size_t ws_size,
                              hipStream_t stream) {
    const float* x = (const float*)d_in[0];
    const int* ei = (const int*)d_in[1];
    const float* W[6] = { (const float*)d_in[2], (const float*)d_in[3],
                          (const float*)d_in[4], (const float*)d_in[5],
                          (const float*)d_in[6], (const float*)d_in[7] };
    const float* bl[3] = { (const float*)d_in[8], (const float*)d_in[9],
                           (const float*)d_in[10] };
    float* out = (float*)d_out;

    const int N = in_sizes[0] / H;      // 50000
    const int E = in_sizes[1] / 2;      // 800000
    const int* src = ei;
    const int* dst = ei + E;

    // workspace carve (256B aligned)
    char* p = (char*)d_ws;
    auto carve = [&](size_t bytes) {
        char* q = p;
        p += (bytes + 255) & ~(size_t)255;
        return q;
    };
    int*            cnt      = (int*)carve((size_t)N * 4);
    int*            row_ptr  = (int*)carve((size_t)(N + 1) * 4);
    int*            cursor   = (int*)carve((size_t)N * 4);
    float*          deg_inv  = (float*)carve((size_t)N * 4);
    int*            csr_src  = (int*)carve((size_t)E * 4);
    int*            blocksum = (int*)carve((size_t)NTHREADS * 4);
    int*            blockoff = (int*)carve((size_t)NTHREADS * 4);
    unsigned short* Bcat     = (unsigned short*)carve((size_t)3 * H * 512 * 2);
    unsigned short* hA       = (unsigned short*)carve((size_t)N * H * 2);
    unsigned short* hB       = (unsigned short*)carve((size_t)N * H * 2);
    unsigned short* aggb     = (unsigned short*)carve((size_t)N * H * 2);

    hipMemsetAsync(cnt, 0, (size_t)N * 4, stream);

    int n4 = N * H / 4;
    cast_x_kernel<<<(n4 + NTHREADS - 1) / NTHREADS, NTHREADS, 0, stream>>>(x, hA, n4);
    for (int l = 0; l < 3; ++l)
        cast_w_kernel<<<(H * 512) / NTHREADS, NTHREADS, 0, stream>>>(
            W[2 * l], W[2 * l + 1], Bcat + (size_t)l * H * 512);

    hist_kernel<<<(E + NTHREADS - 1) / NTHREADS, NTHREADS, 0, stream>>>(dst, cnt, E);

    int nb = (N + NTHREADS - 1) / NTHREADS;   // 196 <= 256
    scan_partial_kernel<<<nb, NTHREADS, 0, stream>>>(cnt, row_ptr, blocksum, N);
    scan_sums_kernel<<<1, NTHREADS, 0, stream>>>(blocksum, blockoff, row_ptr, nb, N);
    scan_finish_kernel<<<nb, NTHREADS, 0, stream>>>(cnt, row_ptr, cursor, deg_inv, blockoff, N);

    fill_kernel<<<(E + NTHREADS - 1) / NTHREADS, NTHREADS, 0, stream>>>(src, dst, cursor, csr_src, E);

    unsigned short* hcur = hA;
    int mtiles = (N + 63) / 64;   // one 64-row block per tile, 4 waves cover N=256
    for (int l = 0; l < 3; ++l) {
        agg_kernel<<<(N + 3) / 4, NTHREADS, 0, stream>>>(hcur, row_ptr, csr_src, deg_inv, aggb, N);
        unsigned short* hnext = (l == 0) ? hB : hA;
        gemm_kernel<<<mtiles, NTHREADS, 0, stream>>>(
            aggb, hcur, Bcat + (size_t)l * H * 512, bl[l],
            (l < 2) ? hnext : nullptr, (l < 2) ? nullptr : out, N);
        hcur = hnext;
    }
}

// Round 5
// 544.427 us; speedup vs baseline: 1.1868x; 1.1868x over previous
//
#include <hip/hip_runtime.h>
#include <hip/hip_bf16.h>

#define H 256
#define NTHREADS 256

// ---------- helpers ----------
static __device__ __forceinline__ float bf2f(unsigned short u) {
    return __uint_as_float(((unsigned int)u) << 16);
}
static __device__ __forceinline__ unsigned short f2bf(float f) {
    unsigned int x = __float_as_uint(f);
    unsigned int r = (x + 0x7fffu + ((x >> 16) & 1u)) >> 16;
    return (unsigned short)r;
}

typedef unsigned short us8 __attribute__((ext_vector_type(8)));

// ---------- cast x (f32 -> bf16) ----------
__global__ __launch_bounds__(NTHREADS) void cast_x_kernel(
    const float* __restrict__ x, unsigned short* __restrict__ h, int n4)
{
    int i = blockIdx.x * NTHREADS + threadIdx.x;
    if (i < n4) {
        float4 v = ((const float4*)x)[i];
        ushort4 o;
        o.x = f2bf(v.x); o.y = f2bf(v.y); o.z = f2bf(v.z); o.w = f2bf(v.w);
        ((ushort4*)h)[i] = o;
    }
}

// ---------- build Bcat[j][k]: k<256 -> Wl[j][k], else Wr[j][k-256] (bf16) ----------
__global__ __launch_bounds__(NTHREADS) void cast_w_kernel(
    const float* __restrict__ Wl, const float* __restrict__ Wr,
    unsigned short* __restrict__ Bcat)
{
    int i = blockIdx.x * NTHREADS + threadIdx.x;   // 256*512 elements
    int j = i >> 9;
    int k = i & 511;
    float v = (k < H) ? Wl[j * H + k] : Wr[j * H + (k - H)];
    Bcat[i] = f2bf(v);
}

// ---------- degree histogram ----------
__global__ __launch_bounds__(NTHREADS) void hist_kernel(
    const int* __restrict__ dst, int* __restrict__ cnt, int E)
{
    int i = blockIdx.x * NTHREADS + threadIdx.x;
    if (i < E) atomicAdd(&cnt[dst[i]], 1);
}

// ---------- multi-block exclusive scan, stage 1: per-block scan ----------
__global__ __launch_bounds__(NTHREADS) void scan_partial_kernel(
    const int* __restrict__ cnt, int* __restrict__ row_ptr,
    int* __restrict__ blocksum, int n_nodes)
{
    __shared__ int tmp[NTHREADS];
    int t = threadIdx.x;
    int i = blockIdx.x * NTHREADS + t;
    int v = (i < n_nodes) ? cnt[i] : 0;
    tmp[t] = v;
    __syncthreads();
#pragma unroll
    for (int d = 1; d < NTHREADS; d <<= 1) {
        int add = (t >= d) ? tmp[t - d] : 0;
        __syncthreads();
        tmp[t] += add;
        __syncthreads();
    }
    if (i < n_nodes) row_ptr[i] = tmp[t] - v;   // exclusive
    if (t == NTHREADS - 1) blocksum[blockIdx.x] = tmp[t];
}

// ---------- stage 2: single block scans block sums (nb <= 256) ----------
__global__ __launch_bounds__(NTHREADS) void scan_sums_kernel(
    int* __restrict__ blocksum, int* __restrict__ blockoff,
    int* __restrict__ row_ptr, int n_blocks, int n_nodes)
{
    __shared__ int tmp[NTHREADS];
    int t = threadIdx.x;
    int v = (t < n_blocks) ? blocksum[t] : 0;
    tmp[t] = v;
    __syncthreads();
#pragma unroll
    for (int d = 1; d < NTHREADS; d <<= 1) {
        int add = (t >= d) ? tmp[t - d] : 0;
        __syncthreads();
        tmp[t] += add;
        __syncthreads();
    }
    if (t < n_blocks) blockoff[t] = tmp[t] - v;  // exclusive
    if (t == NTHREADS - 1) row_ptr[n_nodes] = tmp[t];  // grand total (== E)
}

// ---------- stage 3: add block offsets, init cursor/deg_inv ----------
__global__ __launch_bounds__(NTHREADS) void scan_finish_kernel(
    const int* __restrict__ cnt, int* __restrict__ row_ptr,
    int* __restrict__ cursor, float* __restrict__ deg_inv,
    const int* __restrict__ blockoff, int n_nodes)
{
    int i = blockIdx.x * NTHREADS + threadIdx.x;
    if (i < n_nodes) {
        int r = row_ptr[i] + blockoff[blockIdx.x];
        row_ptr[i] = r;
        cursor[i] = r;
        deg_inv[i] = 1.0f / (float)max(cnt[i], 1);
    }
}

// ---------- scatter edges into CSR order ----------
__global__ __launch_bounds__(NTHREADS) void fill_kernel(
    const int* __restrict__ src, const int* __restrict__ dst,
    int* __restrict__ cursor, int* __restrict__ csr_src, int E)
{
    int i = blockIdx.x * NTHREADS + threadIdx.x;
    if (i < E) {
        int p = atomicAdd(&cursor[dst[i]], 1);
        csr_src[p] = src[i];
    }
}

// ---------- mean aggregation: one wave per node, 16B/lane, 8 edges in flight ----------
// Lanes 0-31 handle even edge of a pair, lanes 32-63 the odd edge (same 8-feature
// chunk each: foff = (lane&31)*8). One 64-lane instruction gathers 2 rows (2x512B).
// Main loop keeps 4 load instructions (8 edges) outstanding. Cross-half combine
// via __shfl_xor(.,32) at the end; lanes 0-31 store the ushort8 result.
__global__ __launch_bounds__(NTHREADS) void agg_kernel(
    const unsigned short* __restrict__ h, const int* __restrict__ row_ptr,
    const int* __restrict__ csr_src, const float* __restrict__ deg_inv,
    unsigned short* __restrict__ agg, int n_nodes)
{
    int wave = threadIdx.x >> 6;
    int lane = threadIdx.x & 63;
    int node = blockIdx.x * 4 + wave;
    if (node >= n_nodes) return;
    int beg = row_ptr[node];
    int cnt = row_ptr[node + 1] - beg;
    const int half = lane >> 5;
    const int foff = (lane & 31) * 8;

    float a[8] = {0.f, 0.f, 0.f, 0.f, 0.f, 0.f, 0.f, 0.f};

    for (int e = 0; e < cnt; e += 64) {
        int rem = min(64, cnt - e);
        int idx = (lane < rem) ? csr_src[beg + e + lane] : 0;
        int j = 0;
        for (; j + 8 <= rem; j += 8) {
            int s0 = __shfl(idx, j + 0 + half);
            int s1 = __shfl(idx, j + 2 + half);
            int s2 = __shfl(idx, j + 4 + half);
            int s3 = __shfl(idx, j + 6 + half);
            us8 v0 = *(const us8*)(h + (size_t)s0 * H + foff);
            us8 v1 = *(const us8*)(h + (size_t)s1 * H + foff);
            us8 v2 = *(const us8*)(h + (size_t)s2 * H + foff);
            us8 v3 = *(const us8*)(h + (size_t)s3 * H + foff);
#pragma unroll
            for (int t = 0; t < 8; ++t) a[t] += bf2f(v0[t]);
#pragma unroll
            for (int t = 0; t < 8; ++t) a[t] += bf2f(v1[t]);
#pragma unroll
            for (int t = 0; t < 8; ++t) a[t] += bf2f(v2[t]);
#pragma unroll
            for (int t = 0; t < 8; ++t) a[t] += bf2f(v3[t]);
        }
        for (; j < rem; j += 2) {
            int jj = j + half;
            int s = __shfl(idx, (jj < rem) ? jj : j);
            if (jj < rem) {
                us8 v = *(const us8*)(h + (size_t)s * H + foff);
#pragma unroll
                for (int t = 0; t < 8; ++t) a[t] += bf2f(v[t]);
            }
        }
    }

#pragma unroll
    for (int t = 0; t < 8; ++t) a[t] += __shfl_xor(a[t], 32);

    if (half == 0) {
        float di = deg_inv[node];
        us8 o;
#pragma unroll
        for (int t = 0; t < 8; ++t) o[t] = f2bf(a[t] * di);
        *(us8*)(agg + (size_t)node * H + foff) = o;
    }
}

// ---------- fused GEMM: out = [agg|hin](M x 512) @ Bcat^T(512 x 256) + bias, ELU ----------
// LDS layout XOR-swizzled: chunk position c of row r holds global 16B-chunk (c ^ (r&7)).
// Staging permutes the global source (LDS dest is forced contiguous by global_load_lds);
// fragment reads un-swizzle. ds_read_b128 spreads rows over all 32 banks (conflict-free).
typedef __bf16 bf16x8 __attribute__((ext_vector_type(8)));
typedef float f32x4 __attribute__((ext_vector_type(4)));

__global__ __launch_bounds__(NTHREADS) void gemm_kernel(
    const unsigned short* __restrict__ Agg, const unsigned short* __restrict__ Hin,
    const unsigned short* __restrict__ Bcat, const float* __restrict__ bias,
    unsigned short* __restrict__ outb, float* __restrict__ outf, int M)
{
    __shared__ __align__(16) unsigned short As[128 * 64];
    __shared__ __align__(16) unsigned short Bs[128 * 64];
    const int tid = threadIdx.x;
    const int lane = tid & 63;
    const int wave = tid >> 6;
    const int m0 = blockIdx.x * 128;
    const int j0 = blockIdx.y * 128;

    f32x4 acc[4][4] = {};

    const int wy = wave >> 1;
    const int wx = wave & 1;
    const int lrow = lane & 15;
    const int kchunk = lane >> 4;         // 0..3

    const int subrow = lane >> 3;
    const int cswz = (lane & 7) ^ (subrow & 7);

    for (int k0 = 0; k0 < 512; k0 += 64) {
        const unsigned short* Aptr;
        int kk;
        if (k0 < 256) { Aptr = Agg; kk = k0; } else { Aptr = Hin; kk = k0 - 256; }
#pragma unroll
        for (int r = 0; r < 4; ++r) {
            int ii = wave * 4 + r;                  // 8-row group index (0..15)
            int row = ii * 8 + subrow;
            int grow = min(m0 + row, M - 1);
            const unsigned short* ga = Aptr + (size_t)grow * H + kk + cswz * 8;
            __builtin_amdgcn_global_load_lds(
                (const __attribute__((address_space(1))) void*)ga,
                (__attribute__((address_space(3))) void*)(As + ii * 512), 16, 0, 0);
        }
#pragma unroll
        for (int r = 0; r < 4; ++r) {
            int ii = wave * 4 + r;
            int row = ii * 8 + subrow;
            const unsigned short* gb = Bcat + (size_t)(j0 + row) * 512 + k0 + cswz * 8;
            __builtin_amdgcn_global_load_lds(
                (const __attribute__((address_space(1))) void*)gb,
                (__attribute__((address_space(3))) void*)(Bs + ii * 512), 16, 0, 0);
        }
        __syncthreads();
#pragma unroll
        for (int kk2 = 0; kk2 < 64; kk2 += 32) {
            const int cid = (kk2 >> 3) + kchunk;    // global chunk id 0..7
            bf16x8 a[4], b[4];
#pragma unroll
            for (int i2 = 0; i2 < 4; ++i2) {
                int row = wy * 64 + i2 * 16 + lrow;
                a[i2] = *(const bf16x8*)(As + row * 64 + ((cid ^ (row & 7)) << 3));
            }
#pragma unroll
            for (int jj = 0; jj < 4; ++jj) {
                int row = wx * 64 + jj * 16 + lrow;
                b[jj] = *(const bf16x8*)(Bs + row * 64 + ((cid ^ (row & 7)) << 3));
            }
#pragma unroll
            for (int i2 = 0; i2 < 4; ++i2)
#pragma unroll
                for (int jj = 0; jj < 4; ++jj)
                    acc[i2][jj] = __builtin_amdgcn_mfma_f32_16x16x32_bf16(
                        a[i2], b[jj], acc[i2][jj], 0, 0, 0);
        }
        __syncthreads();
    }

    // epilogue: bias + ELU; D layout: col = lane&15, row = (lane>>4)*4 + reg
    const int rgrp = (lane >> 4) * 4;
#pragma unroll
    for (int jj = 0; jj < 4; ++jj) {
        int n = j0 + wx * 64 + jj * 16 + lrow;
        float bn = bias[n];
#pragma unroll
        for (int i2 = 0; i2 < 4; ++i2) {
#pragma unroll
            for (int reg = 0; reg < 4; ++reg) {
                int m = m0 + wy * 64 + i2 * 16 + rgrp + reg;
                if (m < M) {
                    float v = acc[i2][jj][reg] + bn;
                    v = (v > 0.f) ? v : expm1f(v);
                    if (outf) outf[(size_t)m * H + n] = v;
                    else      outb[(size_t)m * H + n] = f2bf(v);
                }
            }
        }
    }
}

extern "C" void kernel_launch(void* const* d_in, const int* in_sizes, int n_in,
                              void* d_out, int out_size, void* d_ws, size_t ws_size,
                              hipStream_t stream) {
    const float* x = (const float*)d_in[0];
    const int* ei = (const int*)d_in[1];
    const float* W[6] = { (const float*)d_in[2], (const float*)d_in[3],
                          (const float*)d_in[4], (const float*)d_in[5],
                          (const float*)d_in[6], (const float*)d_in[7] };
    const float* bl[3] = { (const float*)d_in[8], (const float*)d_in[9],
                           (const float*)d_in[10] };
    float* out = (float*)d_out;

    const int N = in_sizes[0] / H;      // 50000
    const int E = in_sizes[1] / 2;      // 800000
    const int* src = ei;
    const int* dst = ei + E;

    // workspace carve (256B aligned)
    char* p = (char*)d_ws;
    auto carve = [&](size_t bytes) {
        char* q = p;
        p += (bytes + 255) & ~(size_t)255;
        return q;
    };
    int*            cnt      = (int*)carve((size_t)N * 4);
    int*            row_ptr  = (int*)carve((size_t)(N + 1) * 4);
    int*            cursor   = (int*)carve((size_t)N * 4);
    float*          deg_inv  = (float*)carve((size_t)N * 4);
    int*            csr_src  = (int*)carve((size_t)E * 4);
    int*            blocksum = (int*)carve((size_t)NTHREADS * 4);
    int*            blockoff = (int*)carve((size_t)NTHREADS * 4);
    unsigned short* Bcat     = (unsigned short*)carve((size_t)3 * H * 512 * 2);
    unsigned short* hA       = (unsigned short*)carve((size_t)N * H * 2);
    unsigned short* hB       = (unsigned short*)carve((size_t)N * H * 2);
    unsigned short* aggb     = (unsigned short*)carve((size_t)N * H * 2);

    hipMemsetAsync(cnt, 0, (size_t)N * 4, stream);

    int n4 = N * H / 4;
    cast_x_kernel<<<(n4 + NTHREADS - 1) / NTHREADS, NTHREADS, 0, stream>>>(x, hA, n4);
    for (int l = 0; l < 3; ++l)
        cast_w_kernel<<<(H * 512) / NTHREADS, NTHREADS, 0, stream>>>(
            W[2 * l], W[2 * l + 1], Bcat + (size_t)l * H * 512);

    hist_kernel<<<(E + NTHREADS - 1) / NTHREADS, NTHREADS, 0, stream>>>(dst, cnt, E);

    int nb = (N + NTHREADS - 1) / NTHREADS;   // 196 <= 256
    scan_partial_kernel<<<nb, NTHREADS, 0, stream>>>(cnt, row_ptr, blocksum, N);
    scan_sums_kernel<<<1, NTHREADS, 0, stream>>>(blocksum, blockoff, row_ptr, nb, N);
    scan_finish_kernel<<<nb, NTHREADS, 0, stream>>>(cnt, row_ptr, cursor, deg_inv, blockoff, N);

    fill_kernel<<<(E + NTHREADS - 1) / NTHREADS, NTHREADS, 0, stream>>>(src, dst, cursor, csr_src, E);

    unsigned short* hcur = hA;
    int mtiles = (N + 127) / 128;
    for (int l = 0; l < 3; ++l) {
        agg_kernel<<<(N + 3) / 4, NTHREADS, 0, stream>>>(hcur, row_ptr, csr_src, deg_inv, aggb, N);
        unsigned short* hnext = (l == 0) ? hB : hA;
        gemm_kernel<<<dim3(mtiles, 2), NTHREADS, 0, stream>>>(
            aggb, hcur, Bcat + (size_t)l * H * 512, bl[l],
            (l < 2) ? hnext : nullptr, (l < 2) ? nullptr : out, N);
        hcur = hnext;
    }
}

// Round 6
// 534.627 us; speedup vs baseline: 1.2085x; 1.0183x over previous
//
#include <hip/hip_runtime.h>
#include <hip/hip_bf16.h>

#define H 256
#define NTHREADS 256

// ---------- helpers ----------
static __device__ __forceinline__ float bf2f(unsigned short u) {
    return __uint_as_float(((unsigned int)u) << 16);
}
static __device__ __forceinline__ unsigned short f2bf(float f) {
    unsigned int x = __float_as_uint(f);
    unsigned int r = (x + 0x7fffu + ((x >> 16) & 1u)) >> 16;
    return (unsigned short)r;
}

typedef unsigned short us8 __attribute__((ext_vector_type(8)));
typedef __bf16 bf16x8 __attribute__((ext_vector_type(8)));
typedef float f32x4 __attribute__((ext_vector_type(4)));

// ---------- cast x (f32 -> bf16) ----------
__global__ __launch_bounds__(NTHREADS) void cast_x_kernel(
    const float* __restrict__ x, unsigned short* __restrict__ h, int n4)
{
    int i = blockIdx.x * NTHREADS + threadIdx.x;
    if (i < n4) {
        float4 v = ((const float4*)x)[i];
        ushort4 o;
        o.x = f2bf(v.x); o.y = f2bf(v.y); o.z = f2bf(v.z); o.w = f2bf(v.w);
        ((ushort4*)h)[i] = o;
    }
}

// ---------- build Bcat2[n][k], n in [0,512): n<256 -> Wl[n][k], else Wr[n-256][k] ----------
__global__ __launch_bounds__(NTHREADS) void cast_w_kernel(
    const float* __restrict__ Wl, const float* __restrict__ Wr,
    unsigned short* __restrict__ Bcat)
{
    int i = blockIdx.x * NTHREADS + threadIdx.x;   // 512*256 elements
    int n = i >> 8;
    int k = i & 255;
    float v = (n < H) ? Wl[n * H + k] : Wr[(n - H) * H + k];
    Bcat[i] = f2bf(v);
}

// ---------- degree histogram ----------
__global__ __launch_bounds__(NTHREADS) void hist_kernel(
    const int* __restrict__ dst, int* __restrict__ cnt, int E)
{
    int i = blockIdx.x * NTHREADS + threadIdx.x;
    if (i < E) atomicAdd(&cnt[dst[i]], 1);
}

// ---------- multi-block exclusive scan, stage 1 ----------
__global__ __launch_bounds__(NTHREADS) void scan_partial_kernel(
    const int* __restrict__ cnt, int* __restrict__ row_ptr,
    int* __restrict__ blocksum, int n_nodes)
{
    __shared__ int tmp[NTHREADS];
    int t = threadIdx.x;
    int i = blockIdx.x * NTHREADS + t;
    int v = (i < n_nodes) ? cnt[i] : 0;
    tmp[t] = v;
    __syncthreads();
#pragma unroll
    for (int d = 1; d < NTHREADS; d <<= 1) {
        int add = (t >= d) ? tmp[t - d] : 0;
        __syncthreads();
        tmp[t] += add;
        __syncthreads();
    }
    if (i < n_nodes) row_ptr[i] = tmp[t] - v;   // exclusive
    if (t == NTHREADS - 1) blocksum[blockIdx.x] = tmp[t];
}

// ---------- stage 2 ----------
__global__ __launch_bounds__(NTHREADS) void scan_sums_kernel(
    int* __restrict__ blocksum, int* __restrict__ blockoff,
    int* __restrict__ row_ptr, int n_blocks, int n_nodes)
{
    __shared__ int tmp[NTHREADS];
    int t = threadIdx.x;
    int v = (t < n_blocks) ? blocksum[t] : 0;
    tmp[t] = v;
    __syncthreads();
#pragma unroll
    for (int d = 1; d < NTHREADS; d <<= 1) {
        int add = (t >= d) ? tmp[t - d] : 0;
        __syncthreads();
        tmp[t] += add;
        __syncthreads();
    }
    if (t < n_blocks) blockoff[t] = tmp[t] - v;
    if (t == NTHREADS - 1) row_ptr[n_nodes] = tmp[t];
}

// ---------- stage 3 ----------
__global__ __launch_bounds__(NTHREADS) void scan_finish_kernel(
    const int* __restrict__ cnt, int* __restrict__ row_ptr,
    int* __restrict__ cursor, float* __restrict__ deg_inv,
    const int* __restrict__ blockoff, int n_nodes)
{
    int i = blockIdx.x * NTHREADS + threadIdx.x;
    if (i < n_nodes) {
        int r = row_ptr[i] + blockoff[blockIdx.x];
        row_ptr[i] = r;
        cursor[i] = r;
        deg_inv[i] = 1.0f / (float)max(cnt[i], 1);
    }
}

// ---------- scatter edges into CSR order ----------
__global__ __launch_bounds__(NTHREADS) void fill_kernel(
    const int* __restrict__ src, const int* __restrict__ dst,
    int* __restrict__ cursor, int* __restrict__ csr_src, int E)
{
    int i = blockIdx.x * NTHREADS + threadIdx.x;
    if (i < E) {
        int p = atomicAdd(&cursor[dst[i]], 1);
        csr_src[p] = src[i];
    }
}

// ---------- GEMM: Y = h(M x 256) @ Bcat2^T -> Yl (bf16, cols 0..255), Yr (f32+bias, cols 256..511)
// K=256 (4 iterations). XOR-swizzled LDS (conflict-free ds_read_b128).
__global__ __launch_bounds__(NTHREADS) void gemm_kernel(
    const unsigned short* __restrict__ Hc, const unsigned short* __restrict__ Bcat,
    const float* __restrict__ bias,
    unsigned short* __restrict__ Yl, float* __restrict__ Yr, int M)
{
    __shared__ __align__(16) unsigned short As[128 * 64];
    __shared__ __align__(16) unsigned short Bs[128 * 64];
    const int tid = threadIdx.x;
    const int lane = tid & 63;
    const int wave = tid >> 6;
    const int m0 = blockIdx.x * 128;
    const int j0 = blockIdx.y * 128;      // 4 n-tiles over N=512

    f32x4 acc[4][4] = {};

    const int wy = wave >> 1;
    const int wx = wave & 1;
    const int lrow = lane & 15;
    const int kchunk = lane >> 4;         // 0..3

    const int subrow = lane >> 3;
    const int cswz = (lane & 7) ^ (subrow & 7);

    for (int k0 = 0; k0 < 256; k0 += 64) {
#pragma unroll
        for (int r = 0; r < 4; ++r) {
            int ii = wave * 4 + r;                  // 8-row group index (0..15)
            int row = ii * 8 + subrow;
            int grow = min(m0 + row, M - 1);
            const unsigned short* ga = Hc + (size_t)grow * H + k0 + cswz * 8;
            __builtin_amdgcn_global_load_lds(
                (const __attribute__((address_space(1))) void*)ga,
                (__attribute__((address_space(3))) void*)(As + ii * 512), 16, 0, 0);
        }
#pragma unroll
        for (int r = 0; r < 4; ++r) {
            int ii = wave * 4 + r;
            int row = ii * 8 + subrow;
            const unsigned short* gb = Bcat + (size_t)(j0 + row) * H + k0 + cswz * 8;
            __builtin_amdgcn_global_load_lds(
                (const __attribute__((address_space(1))) void*)gb,
                (__attribute__((address_space(3))) void*)(Bs + ii * 512), 16, 0, 0);
        }
        __syncthreads();
#pragma unroll
        for (int kk2 = 0; kk2 < 64; kk2 += 32) {
            const int cid = (kk2 >> 3) + kchunk;    // global chunk id 0..7
            bf16x8 a[4], b[4];
#pragma unroll
            for (int i2 = 0; i2 < 4; ++i2) {
                int row = wy * 64 + i2 * 16 + lrow;
                a[i2] = *(const bf16x8*)(As + row * 64 + ((cid ^ (row & 7)) << 3));
            }
#pragma unroll
            for (int jj = 0; jj < 4; ++jj) {
                int row = wx * 64 + jj * 16 + lrow;
                b[jj] = *(const bf16x8*)(Bs + row * 64 + ((cid ^ (row & 7)) << 3));
            }
#pragma unroll
            for (int i2 = 0; i2 < 4; ++i2)
#pragma unroll
                for (int jj = 0; jj < 4; ++jj)
                    acc[i2][jj] = __builtin_amdgcn_mfma_f32_16x16x32_bf16(
                        a[i2], b[jj], acc[i2][jj], 0, 0, 0);
        }
        __syncthreads();
    }

    // epilogue; D layout: col = lane&15, row = (lane>>4)*4 + reg
    // n in [0,512): n<256 -> Yl bf16 (no bias); else Yr f32 with bias
    const int rgrp = (lane >> 4) * 4;
#pragma unroll
    for (int jj = 0; jj < 4; ++jj) {
        int n = j0 + wx * 64 + jj * 16 + lrow;
        bool left = (n < H);                       // wave-uniform (64-col span per wave)
        float bn = left ? 0.f : bias[n - H];
        int nn = left ? n : n - H;
#pragma unroll
        for (int i2 = 0; i2 < 4; ++i2) {
#pragma unroll
            for (int reg = 0; reg < 4; ++reg) {
                int m = m0 + wy * 64 + i2 * 16 + rgrp + reg;
                if (m < M) {
                    float v = acc[i2][jj][reg];
                    if (left) Yl[(size_t)m * H + nn] = f2bf(v);
                    else      Yr[(size_t)m * H + nn] = v + bn;
                }
            }
        }
    }
}

// ---------- fused mean-aggregate(Yl) + Yr + ELU -> next h (bf16) or final out (f32) ----------
// One wave per node; lanes 0-31 even edge, 32-63 odd edge, 8 feats each (foff).
__global__ __launch_bounds__(NTHREADS) void agg_kernel(
    const unsigned short* __restrict__ Yl, const float* __restrict__ Yr,
    const int* __restrict__ row_ptr, const int* __restrict__ csr_src,
    const float* __restrict__ deg_inv,
    unsigned short* __restrict__ outb, float* __restrict__ outf, int n_nodes)
{
    int wave = threadIdx.x >> 6;
    int lane = threadIdx.x & 63;
    int node = blockIdx.x * 4 + wave;
    if (node >= n_nodes) return;
    int beg = row_ptr[node];
    int cnt = row_ptr[node + 1] - beg;
    const int half = lane >> 5;
    const int foff = (lane & 31) * 8;

    float a[8] = {0.f, 0.f, 0.f, 0.f, 0.f, 0.f, 0.f, 0.f};

    for (int e = 0; e < cnt; e += 64) {
        int rem = min(64, cnt - e);
        int idx = (lane < rem) ? csr_src[beg + e + lane] : 0;
        int j = 0;
        for (; j + 8 <= rem; j += 8) {
            int s0 = __shfl(idx, j + 0 + half);
            int s1 = __shfl(idx, j + 2 + half);
            int s2 = __shfl(idx, j + 4 + half);
            int s3 = __shfl(idx, j + 6 + half);
            us8 v0 = *(const us8*)(Yl + (size_t)s0 * H + foff);
            us8 v1 = *(const us8*)(Yl + (size_t)s1 * H + foff);
            us8 v2 = *(const us8*)(Yl + (size_t)s2 * H + foff);
            us8 v3 = *(const us8*)(Yl + (size_t)s3 * H + foff);
#pragma unroll
            for (int t = 0; t < 8; ++t) a[t] += bf2f(v0[t]);
#pragma unroll
            for (int t = 0; t < 8; ++t) a[t] += bf2f(v1[t]);
#pragma unroll
            for (int t = 0; t < 8; ++t) a[t] += bf2f(v2[t]);
#pragma unroll
            for (int t = 0; t < 8; ++t) a[t] += bf2f(v3[t]);
        }
        for (; j < rem; j += 2) {
            int jj = j + half;
            int s = __shfl(idx, (jj < rem) ? jj : j);
            if (jj < rem) {
                us8 v = *(const us8*)(Yl + (size_t)s * H + foff);
#pragma unroll
                for (int t = 0; t < 8; ++t) a[t] += bf2f(v[t]);
            }
        }
    }

#pragma unroll
    for (int t = 0; t < 8; ++t) a[t] += __shfl_xor(a[t], 32);

    if (half == 0) {
        float di = deg_inv[node];
        const float4* yr = (const float4*)(Yr + (size_t)node * H + foff);
        float4 r0 = yr[0], r1 = yr[1];
        float v[8];
        v[0] = a[0] * di + r0.x; v[1] = a[1] * di + r0.y;
        v[2] = a[2] * di + r0.z; v[3] = a[3] * di + r0.w;
        v[4] = a[4] * di + r1.x; v[5] = a[5] * di + r1.y;
        v[6] = a[6] * di + r1.z; v[7] = a[7] * di + r1.w;
#pragma unroll
        for (int t = 0; t < 8; ++t) v[t] = (v[t] > 0.f) ? v[t] : expm1f(v[t]);
        if (outf) {
            float4* o = (float4*)(outf + (size_t)node * H + foff);
            o[0] = make_float4(v[0], v[1], v[2], v[3]);
            o[1] = make_float4(v[4], v[5], v[6], v[7]);
        } else {
            us8 o;
#pragma unroll
            for (int t = 0; t < 8; ++t) o[t] = f2bf(v[t]);
            *(us8*)(outb + (size_t)node * H + foff) = o;
        }
    }
}

extern "C" void kernel_launch(void* const* d_in, const int* in_sizes, int n_in,
                              void* d_out, int out_size, void* d_ws, size_t ws_size,
                              hipStream_t stream) {
    const float* x = (const float*)d_in[0];
    const int* ei = (const int*)d_in[1];
    const float* W[6] = { (const float*)d_in[2], (const float*)d_in[3],
                          (const float*)d_in[4], (const float*)d_in[5],
                          (const float*)d_in[6], (const float*)d_in[7] };
    const float* bl[3] = { (const float*)d_in[8], (const float*)d_in[9],
                           (const float*)d_in[10] };
    float* out = (float*)d_out;

    const int N = in_sizes[0] / H;      // 50000
    const int E = in_sizes[1] / 2;      // 800000
    const int* src = ei;
    const int* dst = ei + E;

    // workspace carve (256B aligned)
    char* p = (char*)d_ws;
    auto carve = [&](size_t bytes) {
        char* q = p;
        p += (bytes + 255) & ~(size_t)255;
        return q;
    };
    int*            cnt      = (int*)carve((size_t)N * 4);
    int*            row_ptr  = (int*)carve((size_t)(N + 1) * 4);
    int*            cursor   = (int*)carve((size_t)N * 4);
    float*          deg_inv  = (float*)carve((size_t)N * 4);
    int*            csr_src  = (int*)carve((size_t)E * 4);
    int*            blocksum = (int*)carve((size_t)NTHREADS * 4);
    int*            blockoff = (int*)carve((size_t)NTHREADS * 4);
    unsigned short* Bcat     = (unsigned short*)carve((size_t)3 * 512 * H * 2);
    unsigned short* hbuf     = (unsigned short*)carve((size_t)N * H * 2);
    unsigned short* Ylb      = (unsigned short*)carve((size_t)N * H * 2);
    float*          Yrb      = (float*)carve((size_t)N * H * 4);

    hipMemsetAsync(cnt, 0, (size_t)N * 4, stream);

    int n4 = N * H / 4;
    cast_x_kernel<<<(n4 + NTHREADS - 1) / NTHREADS, NTHREADS, 0, stream>>>(x, hbuf, n4);
    for (int l = 0; l < 3; ++l)
        cast_w_kernel<<<(512 * H) / NTHREADS, NTHREADS, 0, stream>>>(
            W[2 * l], W[2 * l + 1], Bcat + (size_t)l * 512 * H);

    hist_kernel<<<(E + NTHREADS - 1) / NTHREADS, NTHREADS, 0, stream>>>(dst, cnt, E);

    int nb = (N + NTHREADS - 1) / NTHREADS;   // 196 <= 256
    scan_partial_kernel<<<nb, NTHREADS, 0, stream>>>(cnt, row_ptr, blocksum, N);
    scan_sums_kernel<<<1, NTHREADS, 0, stream>>>(blocksum, blockoff, row_ptr, nb, N);
    scan_finish_kernel<<<nb, NTHREADS, 0, stream>>>(cnt, row_ptr, cursor, deg_inv, blockoff, N);

    fill_kernel<<<(E + NTHREADS - 1) / NTHREADS, NTHREADS, 0, stream>>>(src, dst, cursor, csr_src, E);

    int mtiles = (N + 127) / 128;     // 391
    for (int l = 0; l < 3; ++l) {
        gemm_kernel<<<dim3(mtiles, 4), NTHREADS, 0, stream>>>(
            hbuf, Bcat + (size_t)l * 512 * H, bl[l], Ylb, Yrb, N);
        // agg consumes Yl/Yr; hbuf is free to overwrite (gemm already read it)
        agg_kernel<<<(N + 3) / 4, NTHREADS, 0, stream>>>(
            Ylb, Yrb, row_ptr, csr_src, deg_inv,
            (l < 2) ? hbuf : nullptr, (l < 2) ? nullptr : out, N);
    }
}